// Round 1
// baseline (281.009 us; speedup 1.0000x reference)
//
#include <hip/hip_runtime.h>
#include <cstdint>

#define TT 50
#define II 5
#define PRED 12

typedef _Float16 f16;
typedef _Float16 f16x8 __attribute__((ext_vector_type(8)));
typedef float f32x4 __attribute__((ext_vector_type(4)));

// ---------------- prep: fragment-ordered f16 weights ----------------
// flat f = (((wg*5 + kc)*4 + q)*16 + c)*8 + j, wg = w*4+gsub  (81920 per phase)
// holds Wcat[g][k]: g = gsub*128 + w*16 + c, k = kc*32 + q*8 + j
//   k<128 -> Whh[g][k]; 128..132 -> Wih[g][k-128]; k==133 -> bih[g]+bhh[g]; else 0
__global__ void prep_weights(const float* __restrict__ Wih, const float* __restrict__ Whh,
                             const float* __restrict__ bih, const float* __restrict__ bhh,
                             f16* __restrict__ outw) {
    int f = blockIdx.x * 256 + threadIdx.x;
    if (f >= 81920) return;
    int j  = f & 7;
    int c  = (f >> 3) & 15;
    int q  = (f >> 7) & 3;
    int t2 = f >> 9;              // 0..159
    int kc = t2 % 5;
    int wg = t2 / 5;              // 0..31
    int w = wg >> 2, gsub = wg & 3;
    int g = gsub * 128 + w * 16 + c;
    int k = kc * 32 + q * 8 + j;
    float v;
    if (k < 128)       v = Whh[g * 128 + k];
    else if (k < 133)  v = Wih[g * 5 + (k - 128)];
    else if (k == 133) v = bih[g] + bhh[g];
    else               v = 0.f;
    outw[f] = (f16)v;
}

__device__ __forceinline__ float fsig(float x) {
    return __builtin_amdgcn_rcpf(1.f + __builtin_amdgcn_exp2f(-1.4426950408889634f * x));
}
__device__ __forceinline__ float ftanh(float x) {
    return 1.f - 2.f * __builtin_amdgcn_rcpf(1.f + __builtin_amdgcn_exp2f(2.885390081777927f * x));
}

// ---------------- persistent LSTM kernel ----------------
// 256 blocks x 512 threads; 64 samples/block; state LDS row = 256 f16 (512 B, 32 chunks),
// chunk swizzle: phys = logical ^ (2*(s&15))
__global__ __launch_bounds__(512, 2)
void lstm_kernel(const float* __restrict__ x,
                 const f16* __restrict__ wfrag,      // [2][81920]
                 const float* __restrict__ linW, const float* __restrict__ linB,
                 float* __restrict__ out) {
    __shared__ __align__(16) unsigned char state[64 * 512];
    __shared__ float predpart[8][64][2];

    const int tid  = threadIdx.x;
    const int lane = tid & 63;
    const int w    = tid >> 6;       // wave 0..7
    const int q    = lane >> 4;      // 0..3
    const int cl   = lane & 15;      // 0..15
    const int s0   = blockIdx.x * 64;
    const int jb   = w * 16 + q * 4; // this lane's hidden-j base (rows of its tiles)
    const int physh = ((jb >> 3) ^ (2 * cl)) & 31;   // h-write chunk
    const int hoff  = (jb & 7) * 2;                  // 0 or 8 bytes

    // encoder weight fragments -> registers (80 VGPR)
    f16x8 wr[4][5];
    {
        const f16x8* wp = (const f16x8*)wfrag;
        #pragma unroll
        for (int gs = 0; gs < 4; ++gs) {
            #pragma unroll
            for (int kc = 0; kc < 5; ++kc)
                wr[gs][kc] = wp[((w * 4 + gs) * 5 + kc) * 64 + lane];
        }
    }
    // lin weights for this lane's 4 j rows
    float w0r[4], w1r[4];
    #pragma unroll
    for (int idx = 0; idx < 4; ++idx) {
        w0r[idx] = linW[jb + idx];
        w1r[idx] = linW[128 + jb + idx];
    }
    // static context (tid<64 role)
    float sc0 = 0.f, sc1 = 0.f, sc2 = 0.f;
    if (tid < 64) {
        const float* xr = x + (size_t)(s0 + tid) * (TT * II) + 49 * II;
        sc0 = xr[2]; sc1 = xr[3]; sc2 = xr[4];
    }
    // zero whole state buffer (h0 = 0, zero pad chunks 17..19)
    {
        uint32_t* sp = (uint32_t*)state;
        #pragma unroll
        for (int r = 0; r < 16; ++r) sp[tid + r * 512] = 0u;
    }
    float creg[4][4];
    #pragma unroll
    for (int a = 0; a < 4; ++a)
        #pragma unroll
        for (int b = 0; b < 4; ++b) creg[a][b] = 0.f;

    __syncthreads();
    // chunk16 for t=0: [x0..x4, 1, 0, 0]
    if (tid < 64) {
        const float* xr = x + (size_t)(s0 + tid) * (TT * II);
        union { f16 h[8]; uint4 u; } pk;
        pk.h[0] = (f16)xr[0]; pk.h[1] = (f16)xr[1]; pk.h[2] = (f16)xr[2];
        pk.h[3] = (f16)xr[3]; pk.h[4] = (f16)xr[4];
        pk.h[5] = (f16)1.f; pk.h[6] = (f16)0.f; pk.h[7] = (f16)0.f;
        int phys = 16 ^ (2 * (tid & 15));
        *(uint4*)(state + tid * 512 + phys * 16) = pk.u;
    }
    __syncthreads();

    f32x4 zero4 = {0.f, 0.f, 0.f, 0.f};

    // ===================== encoder =====================
    #pragma unroll 1
    for (int t = 0; t < TT; ++t) {
        // prefetch next x (hidden under K-loop)
        float xv0 = 0, xv1 = 0, xv2 = 0, xv3 = 0, xv4 = 0;
        if (tid < 64) {
            int tn = (t < TT - 1) ? t + 1 : TT - 1;
            const float* xr = x + (size_t)(s0 + tid) * (TT * II) + tn * II;
            xv0 = xr[0]; xv1 = xr[1]; xv2 = xr[2]; xv3 = xr[3]; xv4 = xr[4];
        }
        f32x4 acc[4][4];
        #pragma unroll
        for (int gs = 0; gs < 4; ++gs)
            #pragma unroll
            for (int ns = 0; ns < 4; ++ns) acc[gs][ns] = zero4;

        #pragma unroll
        for (int ns = 0; ns < 4; ++ns) {
            const int srow = ns * 16 + cl;
            #pragma unroll
            for (int kc = 0; kc < 5; ++kc) {
                const int phys = (kc * 4 + q) ^ (2 * cl);
                f16x8 bf = *(const f16x8*)(state + srow * 512 + phys * 16);
                acc[0][ns] = __builtin_amdgcn_mfma_f32_16x16x32_f16(wr[0][kc], bf, acc[0][ns], 0, 0, 0);
                acc[1][ns] = __builtin_amdgcn_mfma_f32_16x16x32_f16(wr[1][kc], bf, acc[1][ns], 0, 0, 0);
                acc[2][ns] = __builtin_amdgcn_mfma_f32_16x16x32_f16(wr[2][kc], bf, acc[2][ns], 0, 0, 0);
                acc[3][ns] = __builtin_amdgcn_mfma_f32_16x16x32_f16(wr[3][kc], bf, acc[3][ns], 0, 0, 0);
            }
        }
        // cell update (register-local: lane owns i/f/g/o for its (s, j))
        uint2 hp[4];
        #pragma unroll
        for (int ns = 0; ns < 4; ++ns) {
            union { f16 h[4]; uint2 u; } pk;
            #pragma unroll
            for (int idx = 0; idx < 4; ++idx) {
                float ii = fsig(acc[0][ns][idx]);
                float ff = fsig(acc[1][ns][idx]);
                float gg = ftanh(acc[2][ns][idx]);
                float oo = fsig(acc[3][ns][idx]);
                float cn = ff * creg[ns][idx] + ii * gg;
                creg[ns][idx] = cn;
                pk.h[idx] = (f16)(oo * ftanh(cn));
            }
            hp[ns] = pk.u;
        }
        __syncthreads();   // A: all state reads done
        #pragma unroll
        for (int ns = 0; ns < 4; ++ns)
            *(uint2*)(state + (ns * 16 + cl) * 512 + physh * 16 + hoff) = hp[ns];
        if (tid < 64) {
            union { f16 h[8]; uint4 u; } pk;
            pk.h[0] = (f16)xv0; pk.h[1] = (f16)xv1; pk.h[2] = (f16)xv2;
            pk.h[3] = (f16)xv3; pk.h[4] = (f16)xv4;
            pk.h[5] = (f16)1.f; pk.h[6] = (f16)0.f; pk.h[7] = (f16)0.f;
            int phys = 16 ^ (2 * (tid & 15));
            *(uint4*)(state + tid * 512 + phys * 16) = pk.u;
        }
        __syncthreads();   // B: writes visible
    }

    // decoder weight fragments
    {
        const f16x8* wp = (const f16x8*)(wfrag + 81920);
        #pragma unroll
        for (int gs = 0; gs < 4; ++gs) {
            #pragma unroll
            for (int kc = 0; kc < 5; ++kc)
                wr[gs][kc] = wp[((w * 4 + gs) * 5 + kc) * 64 + lane];
        }
    }

    // ===================== decoder =====================
    #pragma unroll 1
    for (int td = 0; td < PRED; ++td) {
        f32x4 acc[4][4];
        #pragma unroll
        for (int gs = 0; gs < 4; ++gs)
            #pragma unroll
            for (int ns = 0; ns < 4; ++ns) acc[gs][ns] = zero4;

        #pragma unroll
        for (int ns = 0; ns < 4; ++ns) {
            const int srow = ns * 16 + cl;
            #pragma unroll
            for (int kc = 0; kc < 5; ++kc) {
                const int phys = (kc * 4 + q) ^ (2 * cl);
                f16x8 bf = *(const f16x8*)(state + srow * 512 + phys * 16);
                acc[0][ns] = __builtin_amdgcn_mfma_f32_16x16x32_f16(wr[0][kc], bf, acc[0][ns], 0, 0, 0);
                acc[1][ns] = __builtin_amdgcn_mfma_f32_16x16x32_f16(wr[1][kc], bf, acc[1][ns], 0, 0, 0);
                acc[2][ns] = __builtin_amdgcn_mfma_f32_16x16x32_f16(wr[2][kc], bf, acc[2][ns], 0, 0, 0);
                acc[3][ns] = __builtin_amdgcn_mfma_f32_16x16x32_f16(wr[3][kc], bf, acc[3][ns], 0, 0, 0);
            }
        }
        uint2 hp[4];
        float p0[4], p1[4];
        #pragma unroll
        for (int ns = 0; ns < 4; ++ns) {
            union { f16 h[4]; uint2 u; } pk;
            p0[ns] = 0.f; p1[ns] = 0.f;
            #pragma unroll
            for (int idx = 0; idx < 4; ++idx) {
                float ii = fsig(acc[0][ns][idx]);
                float ff = fsig(acc[1][ns][idx]);
                float gg = ftanh(acc[2][ns][idx]);
                float oo = fsig(acc[3][ns][idx]);
                float cn = ff * creg[ns][idx] + ii * gg;
                creg[ns][idx] = cn;
                float hv = oo * ftanh(cn);
                p0[ns] += hv * w0r[idx];
                p1[ns] += hv * w1r[idx];
                pk.h[idx] = (f16)hv;
            }
            hp[ns] = pk.u;
        }
        // reduce pred partials over q (lanes l, l^16, l^32, l^48 share sample col)
        #pragma unroll
        for (int ns = 0; ns < 4; ++ns) {
            p0[ns] += __shfl_xor(p0[ns], 16);
            p0[ns] += __shfl_xor(p0[ns], 32);
            p1[ns] += __shfl_xor(p1[ns], 16);
            p1[ns] += __shfl_xor(p1[ns], 32);
        }
        if (q == 0) {
            #pragma unroll
            for (int ns = 0; ns < 4; ++ns) {
                predpart[w][ns * 16 + cl][0] = p0[ns];
                predpart[w][ns * 16 + cl][1] = p1[ns];
            }
        }
        __syncthreads();   // A: reads done + predpart ready
        #pragma unroll
        for (int ns = 0; ns < 4; ++ns)
            *(uint2*)(state + (ns * 16 + cl) * 512 + physh * 16 + hoff) = hp[ns];
        if (tid < 64) {
            float a0 = linB[0], a1 = linB[1];
            #pragma unroll
            for (int ww = 0; ww < 8; ++ww) {
                a0 += predpart[ww][tid][0];
                a1 += predpart[ww][tid][1];
            }
            float2 o2; o2.x = a0; o2.y = a1;
            *(float2*)(out + (size_t)(s0 + tid) * (PRED * 2) + td * 2) = o2;
            union { f16 h[8]; uint4 u; } pk;
            pk.h[0] = (f16)a0; pk.h[1] = (f16)a1;
            pk.h[2] = (f16)sc0; pk.h[3] = (f16)sc1; pk.h[4] = (f16)sc2;
            pk.h[5] = (f16)1.f; pk.h[6] = (f16)0.f; pk.h[7] = (f16)0.f;
            int phys = 16 ^ (2 * (tid & 15));
            *(uint4*)(state + tid * 512 + phys * 16) = pk.u;
        }
        __syncthreads();   // B
    }
}

extern "C" void kernel_launch(void* const* d_in, const int* in_sizes, int n_in,
                              void* d_out, int out_size, void* d_ws, size_t ws_size,
                              hipStream_t stream) {
    (void)in_sizes; (void)n_in; (void)out_size; (void)ws_size;
    const float* x    = (const float*)d_in[0];
    const float* eWih = (const float*)d_in[1];
    const float* eWhh = (const float*)d_in[2];
    const float* ebih = (const float*)d_in[3];
    const float* ebhh = (const float*)d_in[4];
    const float* dWih = (const float*)d_in[5];
    const float* dWhh = (const float*)d_in[6];
    const float* dbih = (const float*)d_in[7];
    const float* dbhh = (const float*)d_in[8];
    const float* linW = (const float*)d_in[9];
    const float* linB = (const float*)d_in[10];
    f16* wfrag = (f16*)d_ws;

    prep_weights<<<320, 256, 0, stream>>>(eWih, eWhh, ebih, ebhh, wfrag);
    prep_weights<<<320, 256, 0, stream>>>(dWih, dWhh, dbih, dbhh, wfrag + 81920);
    lstm_kernel<<<256, 512, 0, stream>>>(x, wfrag, linW, linB, (float*)d_out);
}